// Round 2
// baseline (430.355 us; speedup 1.0000x reference)
//
#include <hip/hip_runtime.h>
#include <math.h>

#define BN   32
#define CN   256
#define HWN  4096   // 64*64

// ---------------- workspace layout (floats) ----------------
#define WS_GPART 0        // [b][16][256] per-tile channel partial sums (131072)
#define WS_HT    131072   // h transposed [k=256][b=32] (8192)
#define WS_PHIC  139264   // [b][64] (2048)
#define WS_BAR   149504   // 3 unsigned grid-barrier counters
#define WS_SIGC  149760   // [b][256] (8192)
#define WS_Y     157952   // [b][2][4096] (262144)
#define WS_SIGS  420096   // [b][4096] (131072)

// ---------------- smem layout (floats), 31744 floats = 126976 B -> 1 block/CU ----
// P1 (stats):  csum   [0..16640)   stride-65 [256][65]
//              s_comb [16640..18688) float4[8][64]
//              m_comb [18688..20736) float4[8][64]
// P2 prefetch: wsl    [0..16384)   [k=256][r=64]          (all blocks)
// P2 head scratch (blocks 0..31 only, no overlap with wsl):
//              in_s@26624(320) hs@26944(256) phis@27200(64)
//              hred@27264(512) hred2@27776(512) mbsr@28288(512) pcb@28800(16)
// P3 (cm):     wsl [0..16384) h3 [16384..24576) phi3 [24576..26624)
//              red [26624..30720) red2 [30720..31232) mred [31232..31744)

__global__ __launch_bounds__(64) void k_init(float* __restrict__ ws) {
  if (threadIdx.x < 3) ((unsigned*)(ws + WS_BAR))[threadIdx.x] = 0u;
}

__device__ __forceinline__ void grid_bar(unsigned* ctr) {
  __syncthreads();
  if (threadIdx.x == 0) {
    __threadfence();                               // release: block's stores -> device
    atomicAdd(ctr, 1u);                            // device-scope by default
    while (__hip_atomic_load(ctr, __ATOMIC_ACQUIRE, __HIP_MEMORY_SCOPE_AGENT) < 256u) {
      __builtin_amdgcn_s_sleep(2);
    }
  }
  __syncthreads();
}

__global__ __launch_bounds__(512, 2) void k_fused(
    const float* __restrict__ x,     const float* __restrict__ a,
    const float* __restrict__ W_pre, const float* __restrict__ b_pre,
    const float* __restrict__ W_bc,  const float* __restrict__ b_bc,
    const float* __restrict__ W_bs,  const float* __restrict__ b_bs,
    const float* __restrict__ W_pc,  const float* __restrict__ b_pc,
    const float* __restrict__ W_ps,  const float* __restrict__ b_ps,
    const float* __restrict__ W_Wc,  const float* __restrict__ b_Wc,
    const float* __restrict__ W_Ws,  const float* __restrict__ b_Ws,
    float* __restrict__ out, float* __restrict__ ws) {
  __shared__ __align__(16) float smem[31744];
  const int t = threadIdx.x, blk = blockIdx.x;
  float* gpart   = ws + WS_GPART;
  float* ht      = ws + WS_HT;
  float* phic    = ws + WS_PHIC;
  unsigned* bar  = (unsigned*)(ws + WS_BAR);
  float* sigc    = ws + WS_SIGC;
  float* yws     = ws + WS_Y;
  float* sigs    = ws + WS_SIGS;

  // ================= P1: stats (2 tile-jobs per block, same batch) =============
  {
    int b = blk >> 3;
    int w = t >> 6, l = t & 63;
    const float4* xb = (const float4*)(x + (size_t)b * CN * HWN);
    for (int rep = 0; rep < 2; ++rep) {
      int tile = ((blk & 7) << 1) + rep;
      const float4* xt = xb + tile * 64;
      float4 s4 = {0.f, 0.f, 0.f, 0.f};
      float4 m4 = {-INFINITY, -INFINITY, -INFINITY, -INFINITY};
      int c0 = w << 5;
#pragma unroll 8
      for (int cl = 0; cl < 32; ++cl) {
        int c = c0 + cl;
        float4 v = xt[(size_t)c * 1024 + l];
        s4.x += v.x; s4.y += v.y; s4.z += v.z; s4.w += v.w;
        m4.x = fmaxf(m4.x, v.x); m4.y = fmaxf(m4.y, v.y);
        m4.z = fmaxf(m4.z, v.z); m4.w = fmaxf(m4.w, v.w);
        smem[c * 65 + l] = (v.x + v.y) + (v.z + v.w);  // bank (c+l)%32: conflict-free
      }
      ((float4*)(smem + 16640))[(w << 6) + l] = s4;
      ((float4*)(smem + 18688))[(w << 6) + l] = m4;
      __syncthreads();
      if (t < 256) {  // per-channel 64-px-group reduce (scalar b32, 2-way = free)
        const volatile float* row = smem + t * 65;
        float g0 = 0.f, g1 = 0.f, g2 = 0.f, g3 = 0.f;
#pragma unroll
        for (int j = 0; j < 64; j += 4) {
          g0 += row[j]; g1 += row[j + 1]; g2 += row[j + 2]; g3 += row[j + 3];
        }
        gpart[(((size_t)b * 16 + tile) << 8) + t] = (g0 + g1) + (g2 + g3);
      } else if (t < 320) {  // wave 4: y mean/max combine (wave 0 does gpart)
        int l2 = t - 256;
        const float4* sc4 = (const float4*)(smem + 16640);
        const float4* mc4 = (const float4*)(smem + 18688);
        float4 sa = sc4[l2], ma = mc4[l2];
#pragma unroll
        for (int w2 = 1; w2 < 8; ++w2) {
          float4 s2 = sc4[(w2 << 6) + l2], m2 = mc4[(w2 << 6) + l2];
          sa.x += s2.x; sa.y += s2.y; sa.z += s2.z; sa.w += s2.w;
          ma.x = fmaxf(ma.x, m2.x); ma.y = fmaxf(ma.y, m2.y);
          ma.z = fmaxf(ma.z, m2.z); ma.w = fmaxf(ma.w, m2.w);
        }
        const float inv = 1.0f / 256.0f;
        float4 av = {sa.x * inv, sa.y * inv, sa.z * inv, sa.w * inv};
        ((float4*)(yws + (size_t)b * 2 * HWN + tile * 256))[l2] = av;
        ((float4*)(yws + ((size_t)b * 2 + 1) * HWN + tile * 256))[l2] = ma;
      }
      __syncthreads();
    }
  }
  grid_bar(bar + 0);

  // ================= P2: W_Wc prefetch (all blocks) + head (blocks 0..31) =====
  {
    const float4* col4 = (const float4*)(W_Wc + (size_t)blk * 64);
    float4* wsl4 = (float4*)smem;
#pragma unroll
    for (int j = 0; j < 8; ++j) {
      int i4 = t + (j << 9);
      int k = i4 >> 4, rq = i4 & 15;
      wsl4[i4] = col4[(size_t)k * 4096 + rq];
    }
    if (blk < 32) {
      int b = blk;
      float* in_s  = smem + 26624;
      float* hs    = smem + 26944;
      float* phis  = smem + 27200;
      float* hred  = smem + 27264;
      float* hred2 = smem + 27776;
      float* mbsr  = smem + 28288;
      float* pcb   = smem + 28800;
      if (t < 256) {
        float g = 0.f;
#pragma unroll
        for (int tl = 0; tl < 16; ++tl) g += gpart[(((size_t)b * 16 + tl) << 8) + t];
        in_s[t] = g * (1.0f / 4096.0f);
      } else if (t < 320) {
        in_s[t] = a[(b << 6) + t - 256];
      }
      __syncthreads();
      {  // h: 2 threads/output, k split 160/160
        int o = t & 255, half = t >> 8;
        float acc = half ? 0.f : b_pre[o];
        int k0 = half * 160;
        for (int k = k0; k < k0 + 160; ++k) acc = fmaf(in_s[k], W_pre[(k << 8) + o], acc);
        hred[(half << 8) + o] = acc;
      }
      __syncthreads();
      if (t < 256) {
        float h = fmaxf(hred[t] + hred[256 + t], 0.f);
        hs[t] = h;
        ht[(t << 5) + b] = h;  // transposed [k][b] for P3 staging
      }
      __syncthreads();
      {  // fourier partials: 64 u-values x 8 k-groups of 32
        int ui = t & 63, kg = t >> 6, j = ui & 31;
        const float* Wp = (ui < 32) ? W_pc : W_ps;
        float u = 0.f;
        int k0 = kg << 5;
#pragma unroll 8
        for (int k = k0; k < k0 + 32; ++k) u = fmaf(hs[k], Wp[(k << 6) + j], u);
        hred2[(ui << 3) + kg] = u;
      }
      __syncthreads();
      if (t < 64) {
        int j = t & 31;
        const float* bp = (t < 32) ? b_pc : b_ps;
        float u = bp[j];
#pragma unroll
        for (int g = 0; g < 8; ++g) u += hred2[(t << 3) + g];
        float wj = 1.0f + (float)j * ((3.14159265358979323846f - 1.0f) / 31.0f);
        float su = sinf(u * wj), cu = cosf(u * wj);
        if (t < 32) { phic[(b << 6) + j] = su; phic[(b << 6) + 32 + j] = cu; }
        else        { phis[j] = su; phis[32 + j] = cu; }
      }
      __syncthreads();
      {  // s-branch: 512 outputs, 1 thread each + m_base_s partials
        int r = t & 63;
        float v = b_Ws[t];
        for (int k = 0; k < 256; ++k) v = fmaf(hs[k], W_Ws[(k << 9) + t], v);
        hred[t] = v * phis[r];
        int sg = t & 7, kq = t >> 3;
        float mv = 0.f;
        int k0 = kq << 2;
#pragma unroll
        for (int k = k0; k < k0 + 4; ++k) mv = fmaf(hs[k], W_bs[(k << 3) + sg], mv);
        mbsr[t] = mv;
      }
      __syncthreads();
      if (t < 8) {
        float mbs = b_bs[t];
#pragma unroll
        for (int g = 0; g < 64; ++g) mbs += mbsr[(g << 3) + t];
        float sum = 0.f;
#pragma unroll
        for (int r = 0; r < 64; ++r) sum += hred[(t << 6) + r];
        pcb[t] = mbs * sum;
      }
      __syncthreads();
      if (t == 0) {
        pcb[8] = -(pcb[0] + pcb[1] + pcb[2] + pcb[3]);
        pcb[9] = -(pcb[4] + pcb[5] + pcb[6] + pcb[7]);
      }
      __syncthreads();
      const float* yb = yws + (size_t)b * 2 * HWN;
#pragma unroll
      for (int rep = 0; rep < 8; ++rep) {
        int px = t + (rep << 9);
        int i = px >> 6, j = px & 63;
        float conv = 0.f;
#pragma unroll
        for (int k = 0; k < 2; ++k) {
          const float* yk = yb + (k << 12);
          float up = (i > 0)  ? yk[px - 64] : 0.f;
          float dn = (i < 63) ? yk[px + 64] : 0.f;
          float lf = (j > 0)  ? yk[px - 1]  : 0.f;
          float rt = (j < 63) ? yk[px + 1]  : 0.f;
          conv += pcb[(k << 2) + 0] * up + pcb[(k << 2) + 1] * dn +
                  pcb[(k << 2) + 2] * lf + pcb[(k << 2) + 3] * rt + pcb[8 + k] * yk[px];
        }
        sigs[(b << 12) + px] = 1.f / (1.f + expf(-conv));
      }
    }
  }
  grid_bar(bar + 1);

  // ================= P3: sigc (block = channel c), mbc folded in ==============
  {
    int c = blk;
    float* h3   = smem + 16384;
    float* phi3 = smem + 24576;
    float* red  = smem + 26624;
    float* red2 = smem + 30720;
    float* mred = smem + 31232;
    {
      const float4* ht4 = (const float4*)ht;
      float4* h34 = (float4*)h3;
#pragma unroll
      for (int j = 0; j < 4; ++j) h34[t + (j << 9)] = ht4[t + (j << 9)];
      ((float4*)phi3)[t] = ((const float4*)phic)[t];
    }
    __syncthreads();
    int rq = t & 15, b8 = (t >> 4) & 3, kg = t >> 6;
    const float4* wv = (const float4*)smem;  // wsl (prefetched in P2)
    float4 acc[8];
#pragma unroll
    for (int i = 0; i < 8; ++i) acc[i] = {0.f, 0.f, 0.f, 0.f};
#pragma unroll 4
    for (int kk = 0; kk < 32; ++kk) {
      int k = (kg << 5) + kk;
      float4 w4 = wv[(k << 4) + rq];
      const float4* hp = (const float4*)(h3 + (k << 5) + (b8 << 3));
      float4 h0 = hp[0], h1 = hp[1];
      float hv[8] = {h0.x, h0.y, h0.z, h0.w, h1.x, h1.y, h1.z, h1.w};
#pragma unroll
      for (int i = 0; i < 8; ++i) {
        acc[i].x = fmaf(hv[i], w4.x, acc[i].x);
        acc[i].y = fmaf(hv[i], w4.y, acc[i].y);
        acc[i].z = fmaf(hv[i], w4.z, acc[i].z);
        acc[i].w = fmaf(hv[i], w4.w, acc[i].w);
      }
    }
    {  // mbc partials: b = t&31, 16-k slice each
      int bb = t & 31, kq = t >> 5;
      float mv = 0.f;
      int k0 = kq << 4;
#pragma unroll
      for (int k = k0; k < k0 + 16; ++k) mv = fmaf(h3[(k << 5) + bb], W_bc[(k << 8) + c], mv);
      mred[t] = mv;
    }
    float4 bw = {0.f, 0.f, 0.f, 0.f};
    if (kg == 0) bw = ((const float4*)(b_Wc + (size_t)c * 64))[rq];
#pragma unroll
    for (int i = 0; i < 8; ++i) {
      int bb = (b8 << 3) + i;
      float4 ph = ((const float4*)phi3)[(bb << 4) + rq];
      float4 av = acc[i];
      av.x += bw.x; av.y += bw.y; av.z += bw.z; av.w += bw.w;
      red[((kg << 5) + bb) * 16 + rq] =
          (av.x * ph.x + av.y * ph.y) + (av.z * ph.z + av.w * ph.w);
    }
    __syncthreads();
    {
      int bb = t >> 4, rr = t & 15;
      float tot = 0.f;
#pragma unroll
      for (int g = 0; g < 8; ++g) tot += red[((g << 5) + bb) * 16 + rr];
      red2[t] = tot;
    }
    __syncthreads();
    if (t < 32) {
      float sum = 0.f;
#pragma unroll
      for (int i = 0; i < 16; ++i) sum += red2[(t << 4) + i];
      float mb = b_bc[c];
#pragma unroll
      for (int g = 0; g < 16; ++g) mb += mred[(g << 5) + t];
      float v = mb * sum;
      sigc[(t << 8) + c] = 1.f / (1.f + expf(-v));
    }
  }
  grid_bar(bar + 2);

  // ================= P4: out = x * (1 + sigc + sigs) ==========================
  {
    const float4* x4 = (const float4*)x;
    const float4* s4v = (const float4*)sigs;
    float4* o4 = (float4*)out;
    size_t base = ((size_t)blk << 9) + t;
#pragma unroll 4
    for (int it = 0; it < 64; ++it) {
      size_t idx4 = base + ((size_t)it << 17);
      size_t flat = idx4 << 2;
      int b = (int)(flat >> 20);
      int cc = (int)((flat >> 12) & 255);
      float4 xv = x4[idx4];
      float sc = 1.0f + sigc[(b << 8) + cc];
      float4 ss = s4v[((size_t)b << 10) + (idx4 & 1023)];
      float4 o;
      o.x = xv.x * (sc + ss.x);
      o.y = xv.y * (sc + ss.y);
      o.z = xv.z * (sc + ss.z);
      o.w = xv.w * (sc + ss.w);
      o4[idx4] = o;
    }
  }
}

extern "C" void kernel_launch(void* const* d_in, const int* in_sizes, int n_in,
                              void* d_out, int out_size, void* d_ws, size_t ws_size,
                              hipStream_t stream) {
  const float* x     = (const float*)d_in[0];
  const float* a     = (const float*)d_in[1];
  const float* W_pre = (const float*)d_in[2];
  const float* b_pre = (const float*)d_in[3];
  const float* W_bc  = (const float*)d_in[4];
  const float* b_bc  = (const float*)d_in[5];
  const float* W_bs  = (const float*)d_in[6];
  const float* b_bs  = (const float*)d_in[7];
  const float* W_pc  = (const float*)d_in[8];
  const float* b_pc  = (const float*)d_in[9];
  const float* W_ps  = (const float*)d_in[10];
  const float* b_ps  = (const float*)d_in[11];
  const float* W_Wc  = (const float*)d_in[12];
  const float* b_Wc  = (const float*)d_in[13];
  const float* W_Ws  = (const float*)d_in[14];
  const float* b_Ws  = (const float*)d_in[15];
  float* out = (float*)d_out;
  float* ws  = (float*)d_ws;

  k_init<<<1, 64, 0, stream>>>(ws);
  k_fused<<<256, 512, 0, stream>>>(x, a, W_pre, b_pre, W_bc, b_bc, W_bs, b_bs,
                                   W_pc, b_pc, W_ps, b_ps, W_Wc, b_Wc, W_Ws, b_Ws,
                                   out, ws);
}

// Round 3
// 345.553 us; speedup vs baseline: 1.2454x; 1.2454x over previous
//
#include <hip/hip_runtime.h>
#include <math.h>

#define BN   32
#define CN   256
#define HWN  4096   // 64*64

// ---------------- workspace layout (floats) ----------------
#define WS_GPART 0        // [b][16][256] per-tile channel partial sums (131072)
#define WS_HT    131072   // h transposed [k=256][b=32] (8192)
#define WS_PHIC  139264   // [b][64] (2048)
#define WS_MBC   141312   // [b][256] (8192)
#define WS_SIGC  149760   // [b][256] (8192)
#define WS_Y     157952   // [b][2][4096] (262144)
#define WS_SIGS  420096   // [b][4096] (131072)

// K1: single pass over x with float4 loads. Channel-sum staging split into
// 2 chunks of 128 channels -> LDS 41.3 KB -> 3 blocks/CU (12 waves/CU).
__global__ __launch_bounds__(256, 3) void k_stats(const float* __restrict__ x,
                                                  float* __restrict__ gpart,
                                                  float* __restrict__ y) {
  int b = blockIdx.y, tile = blockIdx.x, t = threadIdx.x;
  int w = t >> 6, l = t & 63;
  __shared__ float csum[128 * 65];   // 33.28 KB, bank (cp+l)%32: conflict-free
  __shared__ float4 s_comb[256];     // 4 KB
  __shared__ float4 m_comb[256];     // 4 KB
  const float4* xt = (const float4*)(x + (size_t)b * CN * HWN) + tile * 64;
  float4 s4 = {0.f, 0.f, 0.f, 0.f};
  float4 m4 = {-INFINITY, -INFINITY, -INFINITY, -INFINITY};
  float* gp = gpart + (((size_t)b * 16 + tile) << 8);
  for (int cc = 0; cc < 2; ++cc) {
    int cbase = cc << 7;
#pragma unroll 8
    for (int cl = 0; cl < 32; ++cl) {
      int cp = (w << 5) + cl;             // 0..127 within chunk
      int c = cbase + cp;
      float4 v = xt[(size_t)c * 1024 + l];
      s4.x += v.x; s4.y += v.y; s4.z += v.z; s4.w += v.w;
      m4.x = fmaxf(m4.x, v.x); m4.y = fmaxf(m4.y, v.y);
      m4.z = fmaxf(m4.z, v.z); m4.w = fmaxf(m4.w, v.w);
      csum[cp * 65 + l] = (v.x + v.y) + (v.z + v.w);
    }
    __syncthreads();
    if (t < 128) {  // per-channel reduce; scalar b32, 2-way aliasing = free
      const volatile float* row = csum + t * 65;
      float g0 = 0.f, g1 = 0.f, g2 = 0.f, g3 = 0.f;
#pragma unroll
      for (int j = 0; j < 64; j += 4) {
        g0 += row[j]; g1 += row[j + 1]; g2 += row[j + 2]; g3 += row[j + 3];
      }
      gp[cbase + t] = (g0 + g1) + (g2 + g3);
    }
    __syncthreads();  // csum reused next chunk
  }
  s_comb[(w << 6) + l] = s4;
  m_comb[(w << 6) + l] = m4;
  __syncthreads();
  if (w == 0) {
    float4 sa = s_comb[l], ma = m_comb[l];
#pragma unroll
    for (int w2 = 1; w2 < 4; ++w2) {
      float4 s2 = s_comb[(w2 << 6) + l], m2 = m_comb[(w2 << 6) + l];
      sa.x += s2.x; sa.y += s2.y; sa.z += s2.z; sa.w += s2.w;
      ma.x = fmaxf(ma.x, m2.x); ma.y = fmaxf(ma.y, m2.y);
      ma.z = fmaxf(ma.z, m2.z); ma.w = fmaxf(ma.w, m2.w);
    }
    const float inv = 1.0f / 256.0f;
    float4 av = {sa.x * inv, sa.y * inv, sa.z * inv, sa.w * inv};
    ((float4*)(y + (size_t)b * 2 * HWN + tile * 256))[l] = av;
    ((float4*)(y + ((size_t)b * 2 + 1) * HWN + tile * 256))[l] = ma;
  }
}

// K2: per-batch MLP head, 512 threads (k-split matvecs) + sigs stencil.
__global__ __launch_bounds__(512) void k_head(
    const float* __restrict__ gpart, const float* __restrict__ a,
    const float* __restrict__ W_pre, const float* __restrict__ b_pre,
    const float* __restrict__ W_bc,  const float* __restrict__ b_bc,
    const float* __restrict__ W_bs,  const float* __restrict__ b_bs,
    const float* __restrict__ W_pc,  const float* __restrict__ b_pc,
    const float* __restrict__ W_ps,  const float* __restrict__ b_ps,
    const float* __restrict__ W_Ws,  const float* __restrict__ b_Ws,
    const float* __restrict__ y,
    float* __restrict__ ht, float* __restrict__ phic,
    float* __restrict__ mbc_out, float* __restrict__ sigs) {
  int b = blockIdx.x, t = threadIdx.x;
  __shared__ float in_s[320], hs[256], phis[64];
  __shared__ float sA[512], sB[512], sC[512], sD[512];
  __shared__ float pcb[16];
  if (t < 256) {
    float g = 0.f;
#pragma unroll
    for (int tl = 0; tl < 16; ++tl) g += gpart[(((size_t)b * 16 + tl) << 8) + t];
    in_s[t] = g * (1.0f / 4096.0f);
  } else if (t < 320) {
    in_s[t] = a[(b << 6) + t - 256];
  }
  __syncthreads();
  {  // h: 2 threads per output, k split 160/160
    int o = t & 255, half = t >> 8;
    float acc = half ? 0.f : b_pre[o];
    int k0 = half * 160;
    for (int k = k0; k < k0 + 160; ++k) acc = fmaf(in_s[k], W_pre[(k << 8) + o], acc);
    sA[(half << 8) + o] = acc;
  }
  __syncthreads();
  if (t < 256) {
    float h = fmaxf(sA[t] + sA[256 + t], 0.f);
    hs[t] = h;
    ht[(t << 5) + b] = h;  // transposed [k][b] for k_cm staging
  }
  __syncthreads();
  {  // fourier partials: 64 u-values x 8 k-groups of 32 -> sB
    int ui = t & 63, kg = t >> 6, j = ui & 31;
    const float* Wp = (ui < 32) ? W_pc : W_ps;
    float u = 0.f;
    int k0 = kg << 5;
#pragma unroll 8
    for (int k = k0; k < k0 + 32; ++k) u = fmaf(hs[k], Wp[(k << 6) + j], u);
    sB[(ui << 3) + kg] = u;
  }
  {  // m_base_c partials: 2 threads per output, k split 128/128 -> sC
    int o = t & 255, half = t >> 8;
    float mb = half ? 0.f : b_bc[o];
    int k0 = half << 7;
    for (int k = k0; k < k0 + 128; ++k) mb = fmaf(hs[k], W_bc[(k << 8) + o], mb);
    sC[(half << 8) + o] = mb;
  }
  __syncthreads();
  if (t < 64) {
    int j = t & 31;
    const float* bp = (t < 32) ? b_pc : b_ps;
    float u = bp[j];
#pragma unroll
    for (int g = 0; g < 8; ++g) u += sB[(t << 3) + g];
    float wj = 1.0f + (float)j * ((3.14159265358979323846f - 1.0f) / 31.0f);
    float su = sinf(u * wj), cu = cosf(u * wj);
    if (t < 32) { phic[(b << 6) + j] = su; phic[(b << 6) + 32 + j] = cu; }
    else        { phis[j] = su; phis[32 + j] = cu; }
  } else if (t >= 256) {
    int o = t - 256;
    mbc_out[(b << 8) + o] = sC[o] + sC[256 + o];
  }
  __syncthreads();
  {  // s-branch: 512 outputs, 1 thread each -> sD ; m_base_s partials -> sA
    int r = t & 63;
    float v = b_Ws[t];
    for (int k = 0; k < 256; ++k) v = fmaf(hs[k], W_Ws[(k << 9) + t], v);
    sD[t] = v * phis[r];
    int sg = t & 7, kq = t >> 3;
    float mv = 0.f;
    int k0 = kq << 2;
#pragma unroll
    for (int k = k0; k < k0 + 4; ++k) mv = fmaf(hs[k], W_bs[(k << 3) + sg], mv);
    sA[t] = mv;
  }
  __syncthreads();
  if (t < 8) {
    float mbs = b_bs[t];
#pragma unroll
    for (int g = 0; g < 64; ++g) mbs += sA[(g << 3) + t];
    float sum = 0.f;
#pragma unroll
    for (int r = 0; r < 64; ++r) sum += sD[(t << 6) + r];
    pcb[t] = mbs * sum;
  }
  __syncthreads();
  if (t == 0) {
    pcb[8] = -(pcb[0] + pcb[1] + pcb[2] + pcb[3]);
    pcb[9] = -(pcb[4] + pcb[5] + pcb[6] + pcb[7]);
  }
  __syncthreads();
  const float* yb = y + (size_t)b * 2 * HWN;
#pragma unroll
  for (int rep = 0; rep < 8; ++rep) {
    int px = t + (rep << 9);
    int i = px >> 6, j = px & 63;
    float conv = 0.f;
#pragma unroll
    for (int k = 0; k < 2; ++k) {
      const float* yk = yb + (k << 12);
      float up = (i > 0)  ? yk[px - 64] : 0.f;
      float dn = (i < 63) ? yk[px + 64] : 0.f;
      float lf = (j > 0)  ? yk[px - 1]  : 0.f;
      float rt = (j < 63) ? yk[px + 1]  : 0.f;
      conv += pcb[(k << 2) + 0] * up + pcb[(k << 2) + 1] * dn +
              pcb[(k << 2) + 2] * lf + pcb[(k << 2) + 3] * rt + pcb[8 + k] * yk[px];
    }
    sigs[(b << 12) + px] = 1.f / (1.f + expf(-conv));
  }
}

// K3: sigc — one block per channel, register-blocked (32 FMA per 3 LDS reads)
__global__ __launch_bounds__(512) void k_cm(
    const float* __restrict__ W_Wc, const float* __restrict__ b_Wc,
    const float* __restrict__ h_t, const float* __restrict__ phic_ws,
    const float* __restrict__ mbc_ws, float* __restrict__ sigc_out) {
  __shared__ __align__(16) float wsl[16384];   // [k=256][r=64]  64 KB
  __shared__ __align__(16) float h_s[8192];    // [k=256][b=32]  32 KB
  __shared__ __align__(16) float phi_s[2048];  // [b=32][r=64]    8 KB
  __shared__ float red[4096];                  // 16 KB
  __shared__ float red2[512];                  // 2 KB
  int t = threadIdx.x, c = blockIdx.x;
  {
    const float4* col4 = (const float4*)(W_Wc + (size_t)c * 64);
    float4* wsl4 = (float4*)wsl;
#pragma unroll
    for (int i4 = t; i4 < 4096; i4 += 512) {
      int k = i4 >> 4, rq = i4 & 15;
      wsl4[i4] = col4[(size_t)k * 4096 + rq];
    }
    const float4* ht4 = (const float4*)h_t;
    float4* hs4 = (float4*)h_s;
#pragma unroll
    for (int i4 = t; i4 < 2048; i4 += 512) hs4[i4] = ht4[i4];
    ((float4*)phi_s)[t] = ((const float4*)phic_ws)[t];
  }
  __syncthreads();
  int rq = t & 15, b8 = (t >> 4) & 3, kg = t >> 6;  // wave-uniform kg
  const float4* wv = (const float4*)wsl;
  float4 acc[8];
#pragma unroll
  for (int i = 0; i < 8; ++i) acc[i] = {0.f, 0.f, 0.f, 0.f};
#pragma unroll 4
  for (int kk = 0; kk < 32; ++kk) {
    int k = (kg << 5) + kk;
    float4 w4 = wv[(k << 4) + rq];
    const float4* hp = (const float4*)(h_s + (k << 5) + (b8 << 3));
    float4 h0 = hp[0], h1 = hp[1];
    float hv[8] = {h0.x, h0.y, h0.z, h0.w, h1.x, h1.y, h1.z, h1.w};
#pragma unroll
    for (int i = 0; i < 8; ++i) {
      acc[i].x = fmaf(hv[i], w4.x, acc[i].x);
      acc[i].y = fmaf(hv[i], w4.y, acc[i].y);
      acc[i].z = fmaf(hv[i], w4.z, acc[i].z);
      acc[i].w = fmaf(hv[i], w4.w, acc[i].w);
    }
  }
  float4 bw = {0.f, 0.f, 0.f, 0.f};
  if (kg == 0) bw = ((const float4*)(b_Wc + (size_t)c * 64))[rq];
#pragma unroll
  for (int i = 0; i < 8; ++i) {
    int bb = (b8 << 3) + i;
    float4 ph = ((const float4*)phi_s)[(bb << 4) + rq];
    float4 av = acc[i];
    av.x += bw.x; av.y += bw.y; av.z += bw.z; av.w += bw.w;
    red[((kg << 5) + bb) * 16 + rq] =
        (av.x * ph.x + av.y * ph.y) + (av.z * ph.z + av.w * ph.w);
  }
  __syncthreads();
  {
    int bb = t >> 4, rr = t & 15;
    float tot = 0.f;
#pragma unroll
    for (int g = 0; g < 8; ++g) tot += red[((g << 5) + bb) * 16 + rr];
    red2[t] = tot;
  }
  __syncthreads();
  if (t < 32) {
    float sum = 0.f;
#pragma unroll
    for (int i = 0; i < 16; ++i) sum += red2[(t << 4) + i];
    float v = mbc_ws[(t << 8) + c] * sum;
    sigc_out[(t << 8) + c] = 1.f / (1.f + expf(-v));
  }
}

// K4: out = x * (1 + sig_c[b,c] + sig_s[b,px])
__global__ __launch_bounds__(256) void k_final(const float* __restrict__ x,
                                               const float* __restrict__ sigc,
                                               const float* __restrict__ sigs,
                                               float* __restrict__ out) {
  size_t idx4 = (size_t)blockIdx.x * 256 + threadIdx.x;
  size_t flat = idx4 * 4;
  int b = (int)(flat >> 20);
  int c = (int)((flat >> 12) & 255);
  int px = (int)(flat & 4095);
  float4 xv = ((const float4*)x)[idx4];
  float sc = 1.0f + sigc[b * 256 + c];
  float4 ss = ((const float4*)sigs)[((size_t)b * HWN + px) >> 2];
  float4 o;
  o.x = xv.x * (sc + ss.x);
  o.y = xv.y * (sc + ss.y);
  o.z = xv.z * (sc + ss.z);
  o.w = xv.w * (sc + ss.w);
  ((float4*)out)[idx4] = o;
}

extern "C" void kernel_launch(void* const* d_in, const int* in_sizes, int n_in,
                              void* d_out, int out_size, void* d_ws, size_t ws_size,
                              hipStream_t stream) {
  const float* x     = (const float*)d_in[0];
  const float* a     = (const float*)d_in[1];
  const float* W_pre = (const float*)d_in[2];
  const float* b_pre = (const float*)d_in[3];
  const float* W_bc  = (const float*)d_in[4];
  const float* b_bc  = (const float*)d_in[5];
  const float* W_bs  = (const float*)d_in[6];
  const float* b_bs  = (const float*)d_in[7];
  const float* W_pc  = (const float*)d_in[8];
  const float* b_pc  = (const float*)d_in[9];
  const float* W_ps  = (const float*)d_in[10];
  const float* b_ps  = (const float*)d_in[11];
  const float* W_Wc  = (const float*)d_in[12];
  const float* b_Wc  = (const float*)d_in[13];
  const float* W_Ws  = (const float*)d_in[14];
  const float* b_Ws  = (const float*)d_in[15];
  float* out = (float*)d_out;
  float* ws  = (float*)d_ws;

  float* gpart_ws = ws + WS_GPART;
  float* ht_ws    = ws + WS_HT;
  float* phic_ws  = ws + WS_PHIC;
  float* mbc_ws   = ws + WS_MBC;
  float* sigc_ws  = ws + WS_SIGC;
  float* y_ws     = ws + WS_Y;
  float* sigs_ws  = ws + WS_SIGS;

  k_stats<<<dim3(16, BN), 256, 0, stream>>>(x, gpart_ws, y_ws);
  k_head<<<BN, 512, 0, stream>>>(gpart_ws, a, W_pre, b_pre, W_bc, b_bc, W_bs, b_bs,
                                 W_pc, b_pc, W_ps, b_ps, W_Ws, b_Ws, y_ws,
                                 ht_ws, phic_ws, mbc_ws, sigs_ws);
  k_cm<<<CN, 512, 0, stream>>>(W_Wc, b_Wc, ht_ws, phic_ws, mbc_ws, sigc_ws);
  k_final<<<(BN * CN * HWN) / 4 / 256, 256, 0, stream>>>(x, sigc_ws, sigs_ws, out);
}

// Round 4
// 329.352 us; speedup vs baseline: 1.3067x; 1.0492x over previous
//
#include <hip/hip_runtime.h>
#include <math.h>

#define BN   32
#define CN   256
#define HWN  4096   // 64*64

// ---------------- workspace layout (floats) ----------------
#define WS_GPART 0        // [b][16][256] per-tile channel partial sums (131072)
#define WS_HT    131072   // h transposed [k=256][b=32] (8192)
#define WS_PHIC  139264   // [b][64] (2048)
#define WS_MBC   141312   // [b][256] (8192)
#define WS_SIGC  149760   // [b][256] (8192)
#define WS_Y     157952   // [b][2][4096] (262144)
#define WS_SIGS  420096   // [b][4096] (131072)

// K1: single pass over x, float4 loads, NO LDS in the main loop.
// Per-channel tile-sum via wave butterfly (the 64 row-sums for channel c are
// wave-resident registers at iteration cl); lane cl keeps channel c0+cl's
// total -> one coalesced 256-float gpart store per block. LDS (8 KB) only
// for the cross-wave y mean/max combine.
__global__ __launch_bounds__(256) void k_stats(const float* __restrict__ x,
                                               float* __restrict__ gpart,
                                               float* __restrict__ y) {
  int b = blockIdx.y, tile = blockIdx.x, t = threadIdx.x;
  int w = t >> 6, l = t & 63;
  __shared__ float4 s_comb[256];   // 4 KB
  __shared__ float4 m_comb[256];   // 4 KB
  const float4* xt = (const float4*)(x + (size_t)b * CN * HWN) + tile * 64;
  float4 s4 = {0.f, 0.f, 0.f, 0.f};
  float4 m4 = {-INFINITY, -INFINITY, -INFINITY, -INFINITY};
  float gval = 0.f;
  int c0 = w << 6;
#pragma unroll 8
  for (int cl = 0; cl < 64; ++cl) {
    float4 v = xt[(size_t)(c0 + cl) * 1024 + l];
    s4.x += v.x; s4.y += v.y; s4.z += v.z; s4.w += v.w;
    m4.x = fmaxf(m4.x, v.x); m4.y = fmaxf(m4.y, v.y);
    m4.z = fmaxf(m4.z, v.z); m4.w = fmaxf(m4.w, v.w);
    float r = (v.x + v.y) + (v.z + v.w);
    r += __shfl_xor(r, 1);
    r += __shfl_xor(r, 2);
    r += __shfl_xor(r, 4);
    r += __shfl_xor(r, 8);
    r += __shfl_xor(r, 16);
    r += __shfl_xor(r, 32);
    if (l == cl) gval = r;   // lane cl owns channel c0+cl
  }
  gpart[(((size_t)b * 16 + tile) << 8) + t] = gval;  // coalesced [c]=t layout
  s_comb[t] = s4;
  m_comb[t] = m4;
  __syncthreads();
  if (w == 0) {
    float4 sa = s_comb[l], ma = m_comb[l];
#pragma unroll
    for (int w2 = 1; w2 < 4; ++w2) {
      float4 s2 = s_comb[(w2 << 6) + l], m2 = m_comb[(w2 << 6) + l];
      sa.x += s2.x; sa.y += s2.y; sa.z += s2.z; sa.w += s2.w;
      ma.x = fmaxf(ma.x, m2.x); ma.y = fmaxf(ma.y, m2.y);
      ma.z = fmaxf(ma.z, m2.z); ma.w = fmaxf(ma.w, m2.w);
    }
    const float inv = 1.0f / 256.0f;
    float4 av = {sa.x * inv, sa.y * inv, sa.z * inv, sa.w * inv};
    ((float4*)(y + (size_t)b * 2 * HWN + tile * 256))[l] = av;
    ((float4*)(y + ((size_t)b * 2 + 1) * HWN + tile * 256))[l] = ma;
  }
}

// K2: per-batch MLP head, 512 threads (k-split matvecs) + sigs stencil.
__global__ __launch_bounds__(512) void k_head(
    const float* __restrict__ gpart, const float* __restrict__ a,
    const float* __restrict__ W_pre, const float* __restrict__ b_pre,
    const float* __restrict__ W_bc,  const float* __restrict__ b_bc,
    const float* __restrict__ W_bs,  const float* __restrict__ b_bs,
    const float* __restrict__ W_pc,  const float* __restrict__ b_pc,
    const float* __restrict__ W_ps,  const float* __restrict__ b_ps,
    const float* __restrict__ W_Ws,  const float* __restrict__ b_Ws,
    const float* __restrict__ y,
    float* __restrict__ ht, float* __restrict__ phic,
    float* __restrict__ mbc_out, float* __restrict__ sigs) {
  int b = blockIdx.x, t = threadIdx.x;
  __shared__ float in_s[320], hs[256], phis[64];
  __shared__ float sA[512], sB[512], sC[512], sD[512];
  __shared__ float pcb[16];
  if (t < 256) {
    float g = 0.f;
#pragma unroll
    for (int tl = 0; tl < 16; ++tl) g += gpart[(((size_t)b * 16 + tl) << 8) + t];
    in_s[t] = g * (1.0f / 4096.0f);
  } else if (t < 320) {
    in_s[t] = a[(b << 6) + t - 256];
  }
  __syncthreads();
  {  // h: 2 threads per output, k split 160/160
    int o = t & 255, half = t >> 8;
    float acc = half ? 0.f : b_pre[o];
    int k0 = half * 160;
    for (int k = k0; k < k0 + 160; ++k) acc = fmaf(in_s[k], W_pre[(k << 8) + o], acc);
    sA[(half << 8) + o] = acc;
  }
  __syncthreads();
  if (t < 256) {
    float h = fmaxf(sA[t] + sA[256 + t], 0.f);
    hs[t] = h;
    ht[(t << 5) + b] = h;  // transposed [k][b] for k_cm staging
  }
  __syncthreads();
  {  // fourier partials: 64 u-values x 8 k-groups of 32 -> sB
    int ui = t & 63, kg = t >> 6, j = ui & 31;
    const float* Wp = (ui < 32) ? W_pc : W_ps;
    float u = 0.f;
    int k0 = kg << 5;
#pragma unroll 8
    for (int k = k0; k < k0 + 32; ++k) u = fmaf(hs[k], Wp[(k << 6) + j], u);
    sB[(ui << 3) + kg] = u;
  }
  {  // m_base_c partials: 2 threads per output, k split 128/128 -> sC
    int o = t & 255, half = t >> 8;
    float mb = half ? 0.f : b_bc[o];
    int k0 = half << 7;
    for (int k = k0; k < k0 + 128; ++k) mb = fmaf(hs[k], W_bc[(k << 8) + o], mb);
    sC[(half << 8) + o] = mb;
  }
  __syncthreads();
  if (t < 64) {
    int j = t & 31;
    const float* bp = (t < 32) ? b_pc : b_ps;
    float u = bp[j];
#pragma unroll
    for (int g = 0; g < 8; ++g) u += sB[(t << 3) + g];
    float wj = 1.0f + (float)j * ((3.14159265358979323846f - 1.0f) / 31.0f);
    float su = sinf(u * wj), cu = cosf(u * wj);
    if (t < 32) { phic[(b << 6) + j] = su; phic[(b << 6) + 32 + j] = cu; }
    else        { phis[j] = su; phis[32 + j] = cu; }
  } else if (t >= 256) {
    int o = t - 256;
    mbc_out[(b << 8) + o] = sC[o] + sC[256 + o];
  }
  __syncthreads();
  {  // s-branch: 512 outputs, 1 thread each -> sD ; m_base_s partials -> sA
    int r = t & 63;
    float v = b_Ws[t];
    for (int k = 0; k < 256; ++k) v = fmaf(hs[k], W_Ws[(k << 9) + t], v);
    sD[t] = v * phis[r];
    int sg = t & 7, kq = t >> 3;
    float mv = 0.f;
    int k0 = kq << 2;
#pragma unroll
    for (int k = k0; k < k0 + 4; ++k) mv = fmaf(hs[k], W_bs[(k << 3) + sg], mv);
    sA[t] = mv;
  }
  __syncthreads();
  if (t < 8) {
    float mbs = b_bs[t];
#pragma unroll
    for (int g = 0; g < 64; ++g) mbs += sA[(g << 3) + t];
    float sum = 0.f;
#pragma unroll
    for (int r = 0; r < 64; ++r) sum += sD[(t << 6) + r];
    pcb[t] = mbs * sum;
  }
  __syncthreads();
  if (t == 0) {
    pcb[8] = -(pcb[0] + pcb[1] + pcb[2] + pcb[3]);
    pcb[9] = -(pcb[4] + pcb[5] + pcb[6] + pcb[7]);
  }
  __syncthreads();
  const float* yb = y + (size_t)b * 2 * HWN;
#pragma unroll
  for (int rep = 0; rep < 8; ++rep) {
    int px = t + (rep << 9);
    int i = px >> 6, j = px & 63;
    float conv = 0.f;
#pragma unroll
    for (int k = 0; k < 2; ++k) {
      const float* yk = yb + (k << 12);
      float up = (i > 0)  ? yk[px - 64] : 0.f;
      float dn = (i < 63) ? yk[px + 64] : 0.f;
      float lf = (j > 0)  ? yk[px - 1]  : 0.f;
      float rt = (j < 63) ? yk[px + 1]  : 0.f;
      conv += pcb[(k << 2) + 0] * up + pcb[(k << 2) + 1] * dn +
              pcb[(k << 2) + 2] * lf + pcb[(k << 2) + 3] * rt + pcb[8 + k] * yk[px];
    }
    sigs[(b << 12) + px] = 1.f / (1.f + expf(-conv));
  }
}

// K3: sigc — one block per channel, register-blocked (32 FMA per 3 LDS reads)
__global__ __launch_bounds__(512) void k_cm(
    const float* __restrict__ W_Wc, const float* __restrict__ b_Wc,
    const float* __restrict__ h_t, const float* __restrict__ phic_ws,
    const float* __restrict__ mbc_ws, float* __restrict__ sigc_out) {
  __shared__ __align__(16) float wsl[16384];   // [k=256][r=64]  64 KB
  __shared__ __align__(16) float h_s[8192];    // [k=256][b=32]  32 KB
  __shared__ __align__(16) float phi_s[2048];  // [b=32][r=64]    8 KB
  __shared__ float red[4096];                  // 16 KB
  __shared__ float red2[512];                  // 2 KB
  int t = threadIdx.x, c = blockIdx.x;
  {
    const float4* col4 = (const float4*)(W_Wc + (size_t)c * 64);
    float4* wsl4 = (float4*)wsl;
#pragma unroll
    for (int i4 = t; i4 < 4096; i4 += 512) {
      int k = i4 >> 4, rq = i4 & 15;
      wsl4[i4] = col4[(size_t)k * 4096 + rq];
    }
    const float4* ht4 = (const float4*)h_t;
    float4* hs4 = (float4*)h_s;
#pragma unroll
    for (int i4 = t; i4 < 2048; i4 += 512) hs4[i4] = ht4[i4];
    ((float4*)phi_s)[t] = ((const float4*)phic_ws)[t];
  }
  __syncthreads();
  int rq = t & 15, b8 = (t >> 4) & 3, kg = t >> 6;  // wave-uniform kg
  const float4* wv = (const float4*)wsl;
  float4 acc[8];
#pragma unroll
  for (int i = 0; i < 8; ++i) acc[i] = {0.f, 0.f, 0.f, 0.f};
#pragma unroll 4
  for (int kk = 0; kk < 32; ++kk) {
    int k = (kg << 5) + kk;
    float4 w4 = wv[(k << 4) + rq];
    const float4* hp = (const float4*)(h_s + (k << 5) + (b8 << 3));
    float4 h0 = hp[0], h1 = hp[1];
    float hv[8] = {h0.x, h0.y, h0.z, h0.w, h1.x, h1.y, h1.z, h1.w};
#pragma unroll
    for (int i = 0; i < 8; ++i) {
      acc[i].x = fmaf(hv[i], w4.x, acc[i].x);
      acc[i].y = fmaf(hv[i], w4.y, acc[i].y);
      acc[i].z = fmaf(hv[i], w4.z, acc[i].z);
      acc[i].w = fmaf(hv[i], w4.w, acc[i].w);
    }
  }
  float4 bw = {0.f, 0.f, 0.f, 0.f};
  if (kg == 0) bw = ((const float4*)(b_Wc + (size_t)c * 64))[rq];
#pragma unroll
  for (int i = 0; i < 8; ++i) {
    int bb = (b8 << 3) + i;
    float4 ph = ((const float4*)phi_s)[(bb << 4) + rq];
    float4 av = acc[i];
    av.x += bw.x; av.y += bw.y; av.z += bw.z; av.w += bw.w;
    red[((kg << 5) + bb) * 16 + rq] =
        (av.x * ph.x + av.y * ph.y) + (av.z * ph.z + av.w * ph.w);
  }
  __syncthreads();
  {
    int bb = t >> 4, rr = t & 15;
    float tot = 0.f;
#pragma unroll
    for (int g = 0; g < 8; ++g) tot += red[((g << 5) + bb) * 16 + rr];
    red2[t] = tot;
  }
  __syncthreads();
  if (t < 32) {
    float sum = 0.f;
#pragma unroll
    for (int i = 0; i < 16; ++i) sum += red2[(t << 4) + i];
    float v = mbc_ws[(t << 8) + c] * sum;
    sigc_out[(t << 8) + c] = 1.f / (1.f + expf(-v));
  }
}

// K4: out = x * (1 + sig_c[b,c] + sig_s[b,px])
__global__ __launch_bounds__(256) void k_final(const float* __restrict__ x,
                                               const float* __restrict__ sigc,
                                               const float* __restrict__ sigs,
                                               float* __restrict__ out) {
  size_t idx4 = (size_t)blockIdx.x * 256 + threadIdx.x;
  size_t flat = idx4 * 4;
  int b = (int)(flat >> 20);
  int c = (int)((flat >> 12) & 255);
  int px = (int)(flat & 4095);
  float4 xv = ((const float4*)x)[idx4];
  float sc = 1.0f + sigc[b * 256 + c];
  float4 ss = ((const float4*)sigs)[((size_t)b * HWN + px) >> 2];
  float4 o;
  o.x = xv.x * (sc + ss.x);
  o.y = xv.y * (sc + ss.y);
  o.z = xv.z * (sc + ss.z);
  o.w = xv.w * (sc + ss.w);
  ((float4*)out)[idx4] = o;
}

extern "C" void kernel_launch(void* const* d_in, const int* in_sizes, int n_in,
                              void* d_out, int out_size, void* d_ws, size_t ws_size,
                              hipStream_t stream) {
  const float* x     = (const float*)d_in[0];
  const float* a     = (const float*)d_in[1];
  const float* W_pre = (const float*)d_in[2];
  const float* b_pre = (const float*)d_in[3];
  const float* W_bc  = (const float*)d_in[4];
  const float* b_bc  = (const float*)d_in[5];
  const float* W_bs  = (const float*)d_in[6];
  const float* b_bs  = (const float*)d_in[7];
  const float* W_pc  = (const float*)d_in[8];
  const float* b_pc  = (const float*)d_in[9];
  const float* W_ps  = (const float*)d_in[10];
  const float* b_ps  = (const float*)d_in[11];
  const float* W_Wc  = (const float*)d_in[12];
  const float* b_Wc  = (const float*)d_in[13];
  const float* W_Ws  = (const float*)d_in[14];
  const float* b_Ws  = (const float*)d_in[15];
  float* out = (float*)d_out;
  float* ws  = (float*)d_ws;

  float* gpart_ws = ws + WS_GPART;
  float* ht_ws    = ws + WS_HT;
  float* phic_ws  = ws + WS_PHIC;
  float* mbc_ws   = ws + WS_MBC;
  float* sigc_ws  = ws + WS_SIGC;
  float* y_ws     = ws + WS_Y;
  float* sigs_ws  = ws + WS_SIGS;

  k_stats<<<dim3(16, BN), 256, 0, stream>>>(x, gpart_ws, y_ws);
  k_head<<<BN, 512, 0, stream>>>(gpart_ws, a, W_pre, b_pre, W_bc, b_bc, W_bs, b_bs,
                                 W_pc, b_pc, W_ps, b_ps, W_Ws, b_Ws, y_ws,
                                 ht_ws, phic_ws, mbc_ws, sigs_ws);
  k_cm<<<CN, 512, 0, stream>>>(W_Wc, b_Wc, ht_ws, phic_ws, mbc_ws, sigc_ws);
  k_final<<<(BN * CN * HWN) / 4 / 256, 256, 0, stream>>>(x, sigc_ws, sigs_ws, out);
}